// Round 14
// baseline (183.341 us; speedup 1.0000x reference)
//
#include <hip/hip_runtime.h>

#define D 100
#define YSTRIDE 128   // bf16 row stride in elements (256 B = 64 uints)
#define BSHIFT 7      // 128 dst nodes per bucket
#define BSIZE 128
#define BMASK 127
#define NBKMAX 512    // supports N <= 65536
#define EPB 1024      // edges per block in the sort pass (halved: 782 blocks, 2x occupancy)
#define BCAP 4096     // per-bucket capacity (edges); mean 2046, max ~2300 for this input
#define WTOT (2 * 7 * 4 * 64)  // 3584 W-fragment rows
#define OSTRIDE 112   // epi LDS out-tile row stride in floats (16B-aligned rows)

typedef __attribute__((ext_vector_type(8))) short bf8v;
typedef __attribute__((ext_vector_type(4))) float f4v;

__device__ inline unsigned short f2bf(float f) {
    unsigned u = __float_as_uint(f);
    return (unsigned short)((u + 0x7fffu + ((u >> 16) & 1u)) >> 16);  // RNE
}
__device__ inline float bflo(unsigned v) { return __uint_as_float(v << 16); }
__device__ inline float bfhi(unsigned v) { return __uint_as_float(v & 0xffff0000u); }
// fp8 e4m3 (OCP on gfx950) helpers
__device__ inline unsigned short pk8(float a, float b) {
    return (unsigned short)(__builtin_amdgcn_cvt_pk_fp8_f32(a, b, 0, false) & 0xffff);
}

// accumulate 8 fp8 values (bytes of a uint2) into acc[0..8), weighted
__device__ inline void acc8(float* acc, uint2 v, float w) {
    acc[0] = fmaf(__builtin_amdgcn_cvt_f32_fp8((int)v.x, 0), w, acc[0]);
    acc[1] = fmaf(__builtin_amdgcn_cvt_f32_fp8((int)v.x, 1), w, acc[1]);
    acc[2] = fmaf(__builtin_amdgcn_cvt_f32_fp8((int)v.x, 2), w, acc[2]);
    acc[3] = fmaf(__builtin_amdgcn_cvt_f32_fp8((int)v.x, 3), w, acc[3]);
    acc[4] = fmaf(__builtin_amdgcn_cvt_f32_fp8((int)v.y, 0), w, acc[4]);
    acc[5] = fmaf(__builtin_amdgcn_cvt_f32_fp8((int)v.y, 1), w, acc[5]);
    acc[6] = fmaf(__builtin_amdgcn_cvt_f32_fp8((int)v.y, 2), w, acc[6]);
    acc[7] = fmaf(__builtin_amdgcn_cvt_f32_fp8((int)v.y, 3), w, acc[7]);
}

// exclusive scan of a[0..512) in LDS, t[256] scratch; 256 threads
__device__ inline void scan512_excl(int* a, int* t, int tid) {
    int v0 = a[2 * tid], v1 = a[2 * tid + 1];
    t[tid] = v0 + v1;
    __syncthreads();
    for (int off = 1; off < 256; off <<= 1) {
        int u = (tid >= off) ? t[tid - off] : 0;
        __syncthreads();
        t[tid] += u;
        __syncthreads();
    }
    int base = (tid ? t[tid - 1] : 0);
    a[2 * tid]     = base;
    a[2 * tid + 1] = base + v0;
    __syncthreads();
}

// ---------------- k_pre: pack x0->fp8 rows | zero bucket counters | Wc = W2*W1 ----------------
__global__ __launch_bounds__(256) void k_pre(const float* __restrict__ x0, const float* __restrict__ W,
                                             unsigned* __restrict__ s8, float* __restrict__ Wc,
                                             int* __restrict__ cur,
                                             int N, int packb) {
    int tid = threadIdx.x;
    int bx = blockIdx.x;

    if (bx < packb) {
        // ---- pack x0 -> fp8 full rows (128 B each) ----
        int t = bx * 256 + tid;
        if (t >= N * 32) return;
        int d = t >> 5, q = t & 31;
        unsigned p = 0u;
        if (q < D / 4) {
            float4 v = *(const float4*)(x0 + (long)d * D + q * 4);
            p = (unsigned)pk8(v.x, v.y) | ((unsigned)pk8(v.z, v.w) << 16);
        }
        s8[t] = p;
    } else if (bx == packb) {
        // ---- zero per-bucket atomic counters ----
        cur[tid] = 0;
        cur[tid + 256] = 0;
    } else {
        // ---- Wc = W2 * W1 (one thread per output element) ----
        int t = (bx - packb - 1) * 256 + tid;
        if (t >= D * D) return;
        int i = t / D, j = t - i * D;
        const float* w2 = W + D * D + (long)i * D;
        float s = 0.f;
        for (int k = 0; k < D; k++) s += w2[k] * W[(long)k * D + j];
        Wc[t] = s;
    }
}

// ---------------- k_sortC: bucketed edge dump into bucket-strided ebuf | W prepack ----------
// Bucket b owns ebuf[b*BCAP ..]; per-(block,bucket) base via one atomicAdd on cur[b].
// Stage/ebuf entry: (bucket << 23) | (dst & 127) << 16 | src   (9+7+16 bits; N <= 65536)
// Dump is per-edge parallel: thread k writes ebuf[runS[b] + (k - lstart[b])].
__global__ __launch_bounds__(256) void k_sortC(const int* __restrict__ src,
                                               const int* __restrict__ dst,
                                               int* __restrict__ cur,
                                               unsigned* __restrict__ ebuf, int E, int nbk,
                                               int nebk,
                                               const float* __restrict__ W1,
                                               const float* __restrict__ Wc,
                                               unsigned short* __restrict__ P) {
    __shared__ int lhist[NBKMAX], lstart[NBKMAX], runS[NBKMAX], t[256];
    __shared__ unsigned stage[EPB];
    int tid = threadIdx.x;

    if ((int)blockIdx.x >= nebk) {
        // ---- W prepack branch (needs Wc from k_pre) ----
        int t2 = ((int)blockIdx.x - nebk) * 256 + tid;
        if (t2 >= WTOT) return;
        int lane = t2 & 63;
        int r = t2 >> 6;
        int kt = r & 3;
        int r2 = r >> 2;
        int nt = r2 % 7;
        int l  = r2 / 7;
        const float* M = (l == 0) ? W1 : Wc;
        int ng = nt * 16 + (lane & 15);
        int k0 = kt * 32 + (lane >> 4) * 8;
        unsigned short u[8];
#pragma unroll
        for (int j = 0; j < 8; j++) {
            int k = k0 + j;
            u[j] = (ng < D && k < D) ? f2bf(M[(long)ng * D + k]) : (unsigned short)0;
        }
        uint4 o;
        o.x = (unsigned)u[0] | ((unsigned)u[1] << 16);
        o.y = (unsigned)u[2] | ((unsigned)u[3] << 16);
        o.z = (unsigned)u[4] | ((unsigned)u[5] << 16);
        o.w = (unsigned)u[6] | ((unsigned)u[7] << 16);
        *(uint4*)(P + (long)t2 * 8) = o;
        return;
    }

    int base = blockIdx.x * EPB;
    int count = min(EPB, E - base);

    for (int i = tid; i < NBKMAX; i += 256) lhist[i] = 0;
    __syncthreads();
    for (int i = tid; i < count; i += 256) atomicAdd(&lhist[dst[base + i] >> BSHIFT], 1);
    __syncthreads();
    for (int i = tid; i < NBKMAX; i += 256) lstart[i] = lhist[i];
    __syncthreads();
    scan512_excl(lstart, t, tid);
    for (int b = tid; b < nbk; b += 256) {
        int c = lhist[b];
        runS[b] = b * BCAP + (c ? atomicAdd(&cur[b], c) : 0);
    }
    __syncthreads();
    for (int i = tid; i < NBKMAX; i += 256) lhist[i] = 0;
    __syncthreads();
    for (int i = tid; i < count; i += 256) {
        int dv = dst[base + i];
        int sv = src[base + i];
        int b = dv >> BSHIFT;
        int r = atomicAdd(&lhist[b], 1);
        stage[lstart[b] + r] = ((unsigned)b << 23) | ((unsigned)(dv & BMASK) << 16) | (unsigned)sv;
    }
    __syncthreads();
    // per-edge parallel dump
    for (int k = tid; k < count; k += 256) {
        unsigned e = stage[k];
        int b = (int)(e >> 23);
        ebuf[runS[b] + (k - lstart[b])] = e;
    }
}

// ---------------- k_csrD: per-bucket CSR finalize at fixed base b*BCAP (512 threads) --------
// Emits rps[d] (edge start, bucket-strided) and rdeg[d] (edge count).
__global__ __launch_bounds__(512) void k_csrD(const unsigned* __restrict__ ebuf,
                                              const int* __restrict__ cur,
                                              int* __restrict__ col,
                                              int* __restrict__ rps, int* __restrict__ rdeg,
                                              int N, int nbk) {
    __shared__ int lh[BSIZE], ls[BSIZE];
    __shared__ int colStage[BCAP];
    int b = blockIdx.x;
    int tid = threadIdx.x;
    int beg = b * BCAP;
    int cnt = cur[b];
    if (cnt > BCAP) cnt = BCAP;  // safety clamp (never hit for this input)

    if (tid < BSIZE) lh[tid] = 0;
    __syncthreads();
    for (int i = tid; i < cnt; i += 512) atomicAdd(&lh[(ebuf[beg + i] >> 16) & BMASK], 1);
    __syncthreads();
    if (tid < BSIZE) ls[tid] = lh[tid];
    __syncthreads();
    for (int off = 1; off < BSIZE; off <<= 1) {
        int v = (tid >= off && tid < BSIZE) ? ls[tid - off] : 0;
        __syncthreads();
        if (tid < BSIZE) ls[tid] += v;
        __syncthreads();
    }
    if (tid < BSIZE) ls[tid] -= lh[tid];
    __syncthreads();
    int d0 = b * BSIZE;
    if (tid < BSIZE && d0 + tid < N) {
        rps[d0 + tid]  = beg + ls[tid];
        rdeg[d0 + tid] = lh[tid];
    }
    if (tid < BSIZE) lh[tid] = 0;
    __syncthreads();
    for (int i = tid; i < cnt; i += 512) {
        unsigned p = ebuf[beg + i];
        int r = (int)((p >> 16) & BMASK), s = (int)(p & 0xffffu);
        int k = atomicAdd(&lh[r], 1);
        colStage[ls[r] + k] = s;
    }
    __syncthreads();
    for (int i = tid; i < cnt; i += 512) col[beg + i] = colStage[i];
}

// ---------------- pure SpMM on fp8 rows: o = (g[d] + sum g[src]) / (deg+1) ----------------
// One wave per dst node. 4 groups of 16 lanes; each group gathers a DIFFERENT src row
// per vmem instruction (16 lanes x dwordx2 = 128 B row).
__global__ __launch_bounds__(256) void k_spmm(const unsigned short* __restrict__ g8,
                                              const int* __restrict__ rps,
                                              const int* __restrict__ rdeg,
                                              const int* __restrict__ col,
                                              const unsigned* __restrict__ self16,
                                              unsigned short* __restrict__ o8,
                                              unsigned* __restrict__ o16,
                                              int write8, int N) {
    int wave = threadIdx.x >> 6;
    int lane = threadIdx.x & 63;
    int g = lane >> 4;
    int j = lane & 15;
    int d = blockIdx.x * 4 + wave;
    if (d >= N) return;

    int b0  = __builtin_amdgcn_readfirstlane(rps[d]);
    int deg = __builtin_amdgcn_readfirstlane(rdeg[d]);
    int e0 = b0 + deg;

    float acc[8];
    // self term: group 0 only (cross-group reduce then counts it exactly once)
    if (g == 0) {
        if (self16) {
            uint4 sv = *((const uint4*)(self16 + (long)d * 64) + j);
            acc[0] = bflo(sv.x); acc[1] = bfhi(sv.x);
            acc[2] = bflo(sv.y); acc[3] = bfhi(sv.y);
            acc[4] = bflo(sv.z); acc[5] = bfhi(sv.z);
            acc[6] = bflo(sv.w); acc[7] = bfhi(sv.w);
        } else {
            uint2 sv = *(const uint2*)(g8 + (long)d * 64 + j * 4);
#pragma unroll
            for (int k = 0; k < 8; k++) acc[k] = 0.f;
            acc8(acc, sv, 1.f);
        }
    } else {
#pragma unroll
        for (int k = 0; k < 8; k++) acc[k] = 0.f;
    }

    for (int win = b0; win < e0; win += 64) {
        int m = e0 - win;
        if (m > 64) m = 64;
        int c = col[win + lane];  // lanes >= m load slack/garbage; never consumed
        int t = 0;
        for (; t + 8 <= m; t += 8) {
            int sa = __shfl(c, t + g);
            int sb = __shfl(c, t + 4 + g);
            uint2 va = *(const uint2*)(g8 + (long)sa * 64 + j * 4);
            uint2 vb = *(const uint2*)(g8 + (long)sb * 64 + j * 4);
            acc8(acc, va, 1.f);
            acc8(acc, vb, 1.f);
        }
        for (; t < m; t += 4) {
            int rem = m - t;
            int idx = t + ((g < rem) ? g : 0);    // clamp keeps shfl source < m (valid)
            int sa = __shfl(c, idx);
            float w = (g < rem) ? 1.f : 0.f;
            uint2 va = *(const uint2*)(g8 + (long)sa * 64 + j * 4);
            acc8(acc, va, w);
        }
    }

    // cross-group butterfly reduce (lane bits 4,5)
#pragma unroll
    for (int k = 0; k < 8; k++) {
        acc[k] += __shfl_xor(acc[k], 16);
        acc[k] += __shfl_xor(acc[k], 32);
    }

    float dinv = 1.f / (float)(deg + 1);
    float r[8];
#pragma unroll
    for (int k = 0; k < 8; k++) r[k] = acc[k] * dinv;

    // dims >= 100 are zero end-to-end (inputs zero-padded), so writes stay zero
    if (g == 0) {
        uint4 o;
        o.x = (unsigned)f2bf(r[0]) | ((unsigned)f2bf(r[1]) << 16);
        o.y = (unsigned)f2bf(r[2]) | ((unsigned)f2bf(r[3]) << 16);
        o.z = (unsigned)f2bf(r[4]) | ((unsigned)f2bf(r[5]) << 16);
        o.w = (unsigned)f2bf(r[6]) | ((unsigned)f2bf(r[7]) << 16);
        *((uint4*)(o16 + (long)d * 64) + j) = o;
    }
    if (write8 && g == 1) {
        uint2 p;
        p.x = (unsigned)pk8(r[0], r[1]) | ((unsigned)pk8(r[2], r[3]) << 16);
        p.y = (unsigned)pk8(r[4], r[5]) | ((unsigned)pk8(r[6], r[7]) << 16);
        *((uint2*)((unsigned*)o8 + (long)d * 32) + j) = p;
    }
}

// ---------------- fused epilogue: x1=u*W1^T, x2=v*Wc^T, norms, out (LDS-staged stores) ----
// Phase 1: each wave computes its 16-row tile into LDS ot[64][OSTRIDE].
// Phase 2: block writes its 64 rows as ONE contiguous span (coalesced float4), fusing the
// x0*invlp1 add into the same coalesced read — kills the 6x partial-line write RMW.
__global__ __launch_bounds__(256) void k_epi(const unsigned short* __restrict__ u16,
                                             const unsigned short* __restrict__ v16,
                                             const unsigned short* __restrict__ P,  // W1 then Wc frags
                                             const float* __restrict__ x0,
                                             float invlp1, float* __restrict__ out, int N) {
    __shared__ float ot[64 * OSTRIDE];  // 28672 B
    int tid = threadIdx.x;
    int wave = tid >> 6;
    int lane = tid & 63;
    int quad = lane >> 4;
    int l16  = lane & 15;
    int blockbase = blockIdx.x * 64;
    int rowbase = blockbase + wave * 16;

    if (rowbase < N) {
        int arow = rowbase + l16;
        if (arow >= N) arow = N - 1;

        bf8v aU[4], aV[4];
        const unsigned short* ur = u16 + (long)arow * YSTRIDE;
        const unsigned short* vr = v16 + (long)arow * YSTRIDE;
#pragma unroll
        for (int kt = 0; kt < 4; kt++) {
            int k0 = kt * 32 + quad * 8;
            union { bf8v v; uint4 u; } a, b;
            a.u = *(const uint4*)(ur + k0);
            b.u = *(const uint4*)(vr + k0);
            aU[kt] = a.v;
            aV[kt] = b.v;
        }

        f4v accU[7], accV[7];
#pragma unroll
        for (int nt = 0; nt < 7; nt++) { accU[nt] = (f4v){0,0,0,0}; accV[nt] = (f4v){0,0,0,0}; }

        const uint4* bp = (const uint4*)P;
#pragma unroll
        for (int nt = 0; nt < 7; nt++) {
#pragma unroll
            for (int kt = 0; kt < 4; kt++) {
                union { uint4 u; bf8v v; } b1, b2;
                b1.u = bp[(nt * 4 + kt) * 64 + lane];
                b2.u = bp[(28 + nt * 4 + kt) * 64 + lane];
                accU[nt] = __builtin_amdgcn_mfma_f32_16x16x32_bf16(aU[kt], b1.v, accU[nt], 0, 0, 0);
                accV[nt] = __builtin_amdgcn_mfma_f32_16x16x32_bf16(aV[kt], b2.v, accV[nt], 0, 0, 0);
            }
        }

        float sU[4], sV[4];
#pragma unroll
        for (int i = 0; i < 4; i++) {
            float nu = 0.f, nv = 0.f;
#pragma unroll
            for (int nt = 0; nt < 7; nt++) {
                nu += accU[nt][i] * accU[nt][i];
                nv += accV[nt][i] * accV[nt][i];
            }
#pragma unroll
            for (int m = 1; m < 16; m <<= 1) {
                nu += __shfl_xor(nu, m);
                nv += __shfl_xor(nv, m);
            }
            sU[i] = invlp1 / fmaxf(sqrtf(nu), 1e-12f);
            sV[i] = invlp1 / fmaxf(sqrtf(nv), 1e-12f);
        }

#pragma unroll
        for (int nt = 0; nt < 7; nt++) {
            int cc = nt * 16 + l16;
            if (cc < D) {
#pragma unroll
                for (int i = 0; i < 4; i++) {
                    int lrow = wave * 16 + quad * 4 + i;
                    ot[lrow * OSTRIDE + cc] = accU[nt][i] * sU[i] + accV[nt][i] * sV[i];
                }
            }
        }
    }
    __syncthreads();

    // ---- phase 2: contiguous coalesced store of this block's rows ----
    int nrows = N - blockbase;
    if (nrows > 64) nrows = 64;
    if (nrows <= 0) return;
    int totalf = nrows * D;            // multiple of 4 (D = 100)
    long gbase = (long)blockbase * D;
    for (int f = tid * 4; f < totalf; f += 256 * 4) {
        int row = f / D;
        int col = f - row * D;
        float4 xv = *(const float4*)(x0 + gbase + f);
        const float* lr = ot + row * OSTRIDE + col;
        float4 ov;
        ov.x = xv.x * invlp1 + lr[0];
        ov.y = xv.y * invlp1 + lr[1];
        ov.z = xv.z * invlp1 + lr[2];
        ov.w = xv.w * invlp1 + lr[3];
        *(float4*)(out + gbase + f) = ov;
    }
}

// ---------------- launcher ----------------

extern "C" void kernel_launch(void* const* d_in, const int* in_sizes, int n_in,
                              void* d_out, int out_size, void* d_ws, size_t ws_size,
                              hipStream_t stream) {
    const float* features = (const float*)d_in[0];
    const float* W        = (const float*)d_in[1];
    const int*   src      = (const int*)d_in[2];
    const int*   dstv     = (const int*)d_in[3];

    int N = in_sizes[0] / D;            // 50000
    int E = in_sizes[2];                // 800000
    int L = in_sizes[1] / (D * D);      // 2 (composition assumes L==2)
    float invlp1 = 1.f / (float)(L + 1);
    int NBK = (N + BSIZE - 1) >> BSHIFT;  // 391
    int nebk = (E + EPB - 1) / EPB;       // 782

    char*  ws  = (char*)d_ws;
    size_t off = 0;
    auto alloc = [&](size_t bytes) -> void* {
        void* p = (void*)(ws + off);
        off += (bytes + 255) & ~(size_t)255;
        return p;
    };
    unsigned*       s8     = (unsigned*)alloc((size_t)N * 32 * sizeof(unsigned));  // fp8 rows (128 B)
    unsigned*       u8     = (unsigned*)alloc((size_t)N * 32 * sizeof(unsigned));  // fp8 rows (128 B)
    unsigned*       u16    = (unsigned*)alloc((size_t)N * 64 * sizeof(unsigned));  // bf16 rows (256 B)
    unsigned*       v16    = (unsigned*)alloc((size_t)N * 64 * sizeof(unsigned));  // bf16 rows (256 B)
    float*          Wc     = (float*)alloc((size_t)D * D * sizeof(float));
    unsigned short* wpack  = (unsigned short*)alloc((size_t)WTOT * 8 * sizeof(unsigned short));
    unsigned*       ebuf   = (unsigned*)alloc((size_t)NBK * BCAP * sizeof(unsigned));  // bucket-strided
    int*            colb   = (int*)alloc((size_t)NBK * BCAP * sizeof(int));            // bucket-strided
    int*            rps    = (int*)alloc((size_t)N * sizeof(int));
    int*            rdeg   = (int*)alloc((size_t)N * sizeof(int));
    int*            cur    = (int*)alloc((size_t)NBKMAX * sizeof(int));

    int packb = (N * 32 + 255) / 256;   // 6250
    int wcb   = (D * D + 255) / 256;    // 40
    int prepb = (WTOT + 255) / 256;     // 14

    // 1: pack | zero cur | Wc
    k_pre<<<packb + 1 + wcb, 256, 0, stream>>>(features, W, s8, Wc, cur, N, packb);
    // 2: bucketed edge dump (parallel per-edge dump, EPB=1024) | W prepack
    k_sortC<<<nebk + prepb, 256, 0, stream>>>(src, dstv, cur, ebuf, E, NBK, nebk, W, Wc, wpack);
    // 3: per-bucket CSR finalize at fixed base (512 threads)
    k_csrD<<<NBK, 512, 0, stream>>>(ebuf, cur, colb, rps, rdeg, N, NBK);

    int spmmblocks = (N + 3) / 4;  // 4 waves x 1 node per block
    // 4: u = A*s0
    k_spmm<<<spmmblocks, 256, 0, stream>>>((const unsigned short*)s8, rps, rdeg, colb,
                                           (const unsigned*)nullptr,
                                           (unsigned short*)u8, u16, 1, N);
    // 5: v = A*u (self from bf16 u16)
    k_spmm<<<spmmblocks, 256, 0, stream>>>((const unsigned short*)u8, rps, rdeg, colb,
                                           u16, (unsigned short*)nullptr, v16, 0, N);

    // 6: epilogue (LDS-staged contiguous stores)
    int epiblocks = (N + 63) / 64;
    k_epi<<<epiblocks, 256, 0, stream>>>((const unsigned short*)u16, (const unsigned short*)v16,
                                         wpack, features, invlp1, (float*)d_out, N);
}

// Round 15
// 175.800 us; speedup vs baseline: 1.0429x; 1.0429x over previous
//
#include <hip/hip_runtime.h>

#define D 100
#define YSTRIDE 128   // bf16 row stride in elements (256 B = 64 uints)
#define BSHIFT 7      // 128 dst nodes per bucket
#define BSIZE 128
#define BMASK 127
#define NBKMAX 512    // supports N <= 65536
#define EPB 2048      // edges per block in the sort pass
#define BCAP 4096     // per-bucket capacity (edges); mean 2046, max ~2300 for this input
#define WTOT (2 * 7 * 4 * 64)  // 3584 W-fragment rows
#define OSTRIDE 112   // epi LDS out-tile row stride in floats (16B-aligned rows)

typedef __attribute__((ext_vector_type(8))) short bf8v;
typedef __attribute__((ext_vector_type(4))) float f4v;

__device__ inline unsigned short f2bf(float f) {
    unsigned u = __float_as_uint(f);
    return (unsigned short)((u + 0x7fffu + ((u >> 16) & 1u)) >> 16);  // RNE
}
__device__ inline float bflo(unsigned v) { return __uint_as_float(v << 16); }
__device__ inline float bfhi(unsigned v) { return __uint_as_float(v & 0xffff0000u); }
// fp8 e4m3 (OCP on gfx950) helpers
__device__ inline unsigned short pk8(float a, float b) {
    return (unsigned short)(__builtin_amdgcn_cvt_pk_fp8_f32(a, b, 0, false) & 0xffff);
}

// accumulate 8 fp8 values (bytes of a uint2) into acc[0..8), weighted
__device__ inline void acc8(float* acc, uint2 v, float w) {
    acc[0] = fmaf(__builtin_amdgcn_cvt_f32_fp8((int)v.x, 0), w, acc[0]);
    acc[1] = fmaf(__builtin_amdgcn_cvt_f32_fp8((int)v.x, 1), w, acc[1]);
    acc[2] = fmaf(__builtin_amdgcn_cvt_f32_fp8((int)v.x, 2), w, acc[2]);
    acc[3] = fmaf(__builtin_amdgcn_cvt_f32_fp8((int)v.x, 3), w, acc[3]);
    acc[4] = fmaf(__builtin_amdgcn_cvt_f32_fp8((int)v.y, 0), w, acc[4]);
    acc[5] = fmaf(__builtin_amdgcn_cvt_f32_fp8((int)v.y, 1), w, acc[5]);
    acc[6] = fmaf(__builtin_amdgcn_cvt_f32_fp8((int)v.y, 2), w, acc[6]);
    acc[7] = fmaf(__builtin_amdgcn_cvt_f32_fp8((int)v.y, 3), w, acc[7]);
}

// exclusive scan of a[0..512) in LDS, t[256] scratch; 256 threads
__device__ inline void scan512_excl(int* a, int* t, int tid) {
    int v0 = a[2 * tid], v1 = a[2 * tid + 1];
    t[tid] = v0 + v1;
    __syncthreads();
    for (int off = 1; off < 256; off <<= 1) {
        int u = (tid >= off) ? t[tid - off] : 0;
        __syncthreads();
        t[tid] += u;
        __syncthreads();
    }
    int base = (tid ? t[tid - 1] : 0);
    a[2 * tid]     = base;
    a[2 * tid + 1] = base + v0;
    __syncthreads();
}

// ---------------- k_pre: pack x0->fp8 rows | zero bucket counters | Wc = W2*W1 ----------------
__global__ __launch_bounds__(256) void k_pre(const float* __restrict__ x0, const float* __restrict__ W,
                                             unsigned* __restrict__ s8, float* __restrict__ Wc,
                                             int* __restrict__ cur,
                                             int N, int packb) {
    int tid = threadIdx.x;
    int bx = blockIdx.x;

    if (bx < packb) {
        // ---- pack x0 -> fp8 full rows (128 B each) ----
        int t = bx * 256 + tid;
        if (t >= N * 32) return;
        int d = t >> 5, q = t & 31;
        unsigned p = 0u;
        if (q < D / 4) {
            float4 v = *(const float4*)(x0 + (long)d * D + q * 4);
            p = (unsigned)pk8(v.x, v.y) | ((unsigned)pk8(v.z, v.w) << 16);
        }
        s8[t] = p;
    } else if (bx == packb) {
        // ---- zero per-bucket atomic counters ----
        cur[tid] = 0;
        cur[tid + 256] = 0;
    } else {
        // ---- Wc = W2 * W1 (one thread per output element) ----
        int t = (bx - packb - 1) * 256 + tid;
        if (t >= D * D) return;
        int i = t / D, j = t - i * D;
        const float* w2 = W + D * D + (long)i * D;
        float s = 0.f;
        for (int k = 0; k < D; k++) s += w2[k] * W[(long)k * D + j];
        Wc[t] = s;
    }
}

// ---------------- k_sortC: bucketed edge dump into bucket-strided ebuf | W prepack ----------
// Bucket b owns ebuf[b*BCAP ..]; per-(block,bucket) base via one atomicAdd on cur[b].
// Stage/ebuf entry: (bucket << 23) | (dst & 127) << 16 | src   (9+7+16 bits; N <= 65536)
// Dump is per-edge parallel: thread k writes ebuf[runS[b] + (k - lstart[b])].
__global__ __launch_bounds__(256) void k_sortC(const int* __restrict__ src,
                                               const int* __restrict__ dst,
                                               int* __restrict__ cur,
                                               unsigned* __restrict__ ebuf, int E, int nbk,
                                               int nebk,
                                               const float* __restrict__ W1,
                                               const float* __restrict__ Wc,
                                               unsigned short* __restrict__ P) {
    __shared__ int lhist[NBKMAX], lstart[NBKMAX], runS[NBKMAX], t[256];
    __shared__ unsigned stage[EPB];
    int tid = threadIdx.x;

    if ((int)blockIdx.x >= nebk) {
        // ---- W prepack branch (needs Wc from k_pre) ----
        int t2 = ((int)blockIdx.x - nebk) * 256 + tid;
        if (t2 >= WTOT) return;
        int lane = t2 & 63;
        int r = t2 >> 6;
        int kt = r & 3;
        int r2 = r >> 2;
        int nt = r2 % 7;
        int l  = r2 / 7;
        const float* M = (l == 0) ? W1 : Wc;
        int ng = nt * 16 + (lane & 15);
        int k0 = kt * 32 + (lane >> 4) * 8;
        unsigned short u[8];
#pragma unroll
        for (int j = 0; j < 8; j++) {
            int k = k0 + j;
            u[j] = (ng < D && k < D) ? f2bf(M[(long)ng * D + k]) : (unsigned short)0;
        }
        uint4 o;
        o.x = (unsigned)u[0] | ((unsigned)u[1] << 16);
        o.y = (unsigned)u[2] | ((unsigned)u[3] << 16);
        o.z = (unsigned)u[4] | ((unsigned)u[5] << 16);
        o.w = (unsigned)u[6] | ((unsigned)u[7] << 16);
        *(uint4*)(P + (long)t2 * 8) = o;
        return;
    }

    int base = blockIdx.x * EPB;
    int count = min(EPB, E - base);

    for (int i = tid; i < NBKMAX; i += 256) lhist[i] = 0;
    __syncthreads();
    for (int i = tid; i < count; i += 256) atomicAdd(&lhist[dst[base + i] >> BSHIFT], 1);
    __syncthreads();
    for (int i = tid; i < NBKMAX; i += 256) lstart[i] = lhist[i];
    __syncthreads();
    scan512_excl(lstart, t, tid);
    for (int b = tid; b < nbk; b += 256) {
        int c = lhist[b];
        runS[b] = b * BCAP + (c ? atomicAdd(&cur[b], c) : 0);
    }
    __syncthreads();
    for (int i = tid; i < NBKMAX; i += 256) lhist[i] = 0;
    __syncthreads();
    for (int i = tid; i < count; i += 256) {
        int dv = dst[base + i];
        int sv = src[base + i];
        int b = dv >> BSHIFT;
        int r = atomicAdd(&lhist[b], 1);
        stage[lstart[b] + r] = ((unsigned)b << 23) | ((unsigned)(dv & BMASK) << 16) | (unsigned)sv;
    }
    __syncthreads();
    // per-edge parallel dump
    for (int k = tid; k < count; k += 256) {
        unsigned e = stage[k];
        int b = (int)(e >> 23);
        ebuf[runS[b] + (k - lstart[b])] = e;
    }
}

// ---------------- k_csrD: per-bucket CSR finalize at fixed base b*BCAP ----------------
// Emits rps[d] (edge start, bucket-strided) and rdeg[d] (edge count).
__global__ __launch_bounds__(256) void k_csrD(const unsigned* __restrict__ ebuf,
                                              const int* __restrict__ cur,
                                              int* __restrict__ col,
                                              int* __restrict__ rps, int* __restrict__ rdeg,
                                              int N, int nbk) {
    __shared__ int lh[BSIZE], ls[BSIZE];
    __shared__ int colStage[BCAP];
    int b = blockIdx.x;
    int tid = threadIdx.x;
    int beg = b * BCAP;
    int cnt = cur[b];
    if (cnt > BCAP) cnt = BCAP;  // safety clamp (never hit for this input)

    if (tid < BSIZE) lh[tid] = 0;
    __syncthreads();
    for (int i = tid; i < cnt; i += 256) atomicAdd(&lh[(ebuf[beg + i] >> 16) & BMASK], 1);
    __syncthreads();
    if (tid < BSIZE) ls[tid] = lh[tid];
    __syncthreads();
    for (int off = 1; off < BSIZE; off <<= 1) {
        int v = (tid >= off && tid < BSIZE) ? ls[tid - off] : 0;
        __syncthreads();
        if (tid < BSIZE) ls[tid] += v;
        __syncthreads();
    }
    if (tid < BSIZE) ls[tid] -= lh[tid];
    __syncthreads();
    int d0 = b * BSIZE;
    if (tid < BSIZE && d0 + tid < N) {
        rps[d0 + tid]  = beg + ls[tid];
        rdeg[d0 + tid] = lh[tid];
    }
    if (tid < BSIZE) lh[tid] = 0;
    __syncthreads();
    for (int i = tid; i < cnt; i += 256) {
        unsigned p = ebuf[beg + i];
        int r = (int)((p >> 16) & BMASK), s = (int)(p & 0xffffu);
        int k = atomicAdd(&lh[r], 1);
        colStage[ls[r] + k] = s;
    }
    __syncthreads();
    for (int i = tid; i < cnt; i += 256) col[beg + i] = colStage[i];
}

// ---------------- pure SpMM on fp8 rows: o = (g[d] + sum g[src]) / (deg+1) ----------------
// One wave per dst node. 4 groups of 16 lanes; each group gathers a DIFFERENT src row
// per vmem instruction (16 lanes x dwordx2 = 128 B row).
__global__ __launch_bounds__(256) void k_spmm(const unsigned short* __restrict__ g8,
                                              const int* __restrict__ rps,
                                              const int* __restrict__ rdeg,
                                              const int* __restrict__ col,
                                              const unsigned* __restrict__ self16,
                                              unsigned short* __restrict__ o8,
                                              unsigned* __restrict__ o16,
                                              int write8, int N) {
    int wave = threadIdx.x >> 6;
    int lane = threadIdx.x & 63;
    int g = lane >> 4;
    int j = lane & 15;
    int d = blockIdx.x * 4 + wave;
    if (d >= N) return;

    int b0  = __builtin_amdgcn_readfirstlane(rps[d]);
    int deg = __builtin_amdgcn_readfirstlane(rdeg[d]);
    int e0 = b0 + deg;

    float acc[8];
    // self term: group 0 only (cross-group reduce then counts it exactly once)
    if (g == 0) {
        if (self16) {
            uint4 sv = *((const uint4*)(self16 + (long)d * 64) + j);
            acc[0] = bflo(sv.x); acc[1] = bfhi(sv.x);
            acc[2] = bflo(sv.y); acc[3] = bfhi(sv.y);
            acc[4] = bflo(sv.z); acc[5] = bfhi(sv.z);
            acc[6] = bflo(sv.w); acc[7] = bfhi(sv.w);
        } else {
            uint2 sv = *(const uint2*)(g8 + (long)d * 64 + j * 4);
#pragma unroll
            for (int k = 0; k < 8; k++) acc[k] = 0.f;
            acc8(acc, sv, 1.f);
        }
    } else {
#pragma unroll
        for (int k = 0; k < 8; k++) acc[k] = 0.f;
    }

    for (int win = b0; win < e0; win += 64) {
        int m = e0 - win;
        if (m > 64) m = 64;
        int c = col[win + lane];  // lanes >= m load slack/garbage; never consumed
        int t = 0;
        for (; t + 8 <= m; t += 8) {
            int sa = __shfl(c, t + g);
            int sb = __shfl(c, t + 4 + g);
            uint2 va = *(const uint2*)(g8 + (long)sa * 64 + j * 4);
            uint2 vb = *(const uint2*)(g8 + (long)sb * 64 + j * 4);
            acc8(acc, va, 1.f);
            acc8(acc, vb, 1.f);
        }
        for (; t < m; t += 4) {
            int rem = m - t;
            int idx = t + ((g < rem) ? g : 0);    // clamp keeps shfl source < m (valid)
            int sa = __shfl(c, idx);
            float w = (g < rem) ? 1.f : 0.f;
            uint2 va = *(const uint2*)(g8 + (long)sa * 64 + j * 4);
            acc8(acc, va, w);
        }
    }

    // cross-group butterfly reduce (lane bits 4,5)
#pragma unroll
    for (int k = 0; k < 8; k++) {
        acc[k] += __shfl_xor(acc[k], 16);
        acc[k] += __shfl_xor(acc[k], 32);
    }

    float dinv = 1.f / (float)(deg + 1);
    float r[8];
#pragma unroll
    for (int k = 0; k < 8; k++) r[k] = acc[k] * dinv;

    // dims >= 100 are zero end-to-end (inputs zero-padded), so writes stay zero
    if (g == 0) {
        uint4 o;
        o.x = (unsigned)f2bf(r[0]) | ((unsigned)f2bf(r[1]) << 16);
        o.y = (unsigned)f2bf(r[2]) | ((unsigned)f2bf(r[3]) << 16);
        o.z = (unsigned)f2bf(r[4]) | ((unsigned)f2bf(r[5]) << 16);
        o.w = (unsigned)f2bf(r[6]) | ((unsigned)f2bf(r[7]) << 16);
        *((uint4*)(o16 + (long)d * 64) + j) = o;
    }
    if (write8 && g == 1) {
        uint2 p;
        p.x = (unsigned)pk8(r[0], r[1]) | ((unsigned)pk8(r[2], r[3]) << 16);
        p.y = (unsigned)pk8(r[4], r[5]) | ((unsigned)pk8(r[6], r[7]) << 16);
        *((uint2*)((unsigned*)o8 + (long)d * 32) + j) = p;
    }
}

// ---------------- fused epilogue: x1=u*W1^T, x2=v*Wc^T, norms, out (LDS-staged stores) ----
// Phase 1: each wave computes its 16-row tile into LDS ot[64][OSTRIDE].
// Phase 2: block writes its 64 rows as ONE contiguous span (coalesced float4), fusing the
// x0*invlp1 add into the same coalesced read — kills the 6x partial-line write RMW.
__global__ __launch_bounds__(256) void k_epi(const unsigned short* __restrict__ u16,
                                             const unsigned short* __restrict__ v16,
                                             const unsigned short* __restrict__ P,  // W1 then Wc frags
                                             const float* __restrict__ x0,
                                             float invlp1, float* __restrict__ out, int N) {
    __shared__ float ot[64 * OSTRIDE];  // 28672 B
    int tid = threadIdx.x;
    int wave = tid >> 6;
    int lane = tid & 63;
    int quad = lane >> 4;
    int l16  = lane & 15;
    int blockbase = blockIdx.x * 64;
    int rowbase = blockbase + wave * 16;

    if (rowbase < N) {
        int arow = rowbase + l16;
        if (arow >= N) arow = N - 1;

        bf8v aU[4], aV[4];
        const unsigned short* ur = u16 + (long)arow * YSTRIDE;
        const unsigned short* vr = v16 + (long)arow * YSTRIDE;
#pragma unroll
        for (int kt = 0; kt < 4; kt++) {
            int k0 = kt * 32 + quad * 8;
            union { bf8v v; uint4 u; } a, b;
            a.u = *(const uint4*)(ur + k0);
            b.u = *(const uint4*)(vr + k0);
            aU[kt] = a.v;
            aV[kt] = b.v;
        }

        f4v accU[7], accV[7];
#pragma unroll
        for (int nt = 0; nt < 7; nt++) { accU[nt] = (f4v){0,0,0,0}; accV[nt] = (f4v){0,0,0,0}; }

        const uint4* bp = (const uint4*)P;
#pragma unroll
        for (int nt = 0; nt < 7; nt++) {
#pragma unroll
            for (int kt = 0; kt < 4; kt++) {
                union { uint4 u; bf8v v; } b1, b2;
                b1.u = bp[(nt * 4 + kt) * 64 + lane];
                b2.u = bp[(28 + nt * 4 + kt) * 64 + lane];
                accU[nt] = __builtin_amdgcn_mfma_f32_16x16x32_bf16(aU[kt], b1.v, accU[nt], 0, 0, 0);
                accV[nt] = __builtin_amdgcn_mfma_f32_16x16x32_bf16(aV[kt], b2.v, accV[nt], 0, 0, 0);
            }
        }

        float sU[4], sV[4];
#pragma unroll
        for (int i = 0; i < 4; i++) {
            float nu = 0.f, nv = 0.f;
#pragma unroll
            for (int nt = 0; nt < 7; nt++) {
                nu += accU[nt][i] * accU[nt][i];
                nv += accV[nt][i] * accV[nt][i];
            }
#pragma unroll
            for (int m = 1; m < 16; m <<= 1) {
                nu += __shfl_xor(nu, m);
                nv += __shfl_xor(nv, m);
            }
            sU[i] = invlp1 / fmaxf(sqrtf(nu), 1e-12f);
            sV[i] = invlp1 / fmaxf(sqrtf(nv), 1e-12f);
        }

#pragma unroll
        for (int nt = 0; nt < 7; nt++) {
            int cc = nt * 16 + l16;
            if (cc < D) {
#pragma unroll
                for (int i = 0; i < 4; i++) {
                    int lrow = wave * 16 + quad * 4 + i;
                    ot[lrow * OSTRIDE + cc] = accU[nt][i] * sU[i] + accV[nt][i] * sV[i];
                }
            }
        }
    }
    __syncthreads();

    // ---- phase 2: contiguous coalesced store of this block's rows ----
    int nrows = N - blockbase;
    if (nrows > 64) nrows = 64;
    if (nrows <= 0) return;
    int totalf = nrows * D;            // multiple of 4 (D = 100)
    long gbase = (long)blockbase * D;
    for (int f = tid * 4; f < totalf; f += 256 * 4) {
        int row = f / D;
        int col = f - row * D;
        float4 xv = *(const float4*)(x0 + gbase + f);
        const float* lr = ot + row * OSTRIDE + col;
        float4 ov;
        ov.x = xv.x * invlp1 + lr[0];
        ov.y = xv.y * invlp1 + lr[1];
        ov.z = xv.z * invlp1 + lr[2];
        ov.w = xv.w * invlp1 + lr[3];
        *(float4*)(out + gbase + f) = ov;
    }
}

// ---------------- launcher ----------------

extern "C" void kernel_launch(void* const* d_in, const int* in_sizes, int n_in,
                              void* d_out, int out_size, void* d_ws, size_t ws_size,
                              hipStream_t stream) {
    const float* features = (const float*)d_in[0];
    const float* W        = (const float*)d_in[1];
    const int*   src      = (const int*)d_in[2];
    const int*   dstv     = (const int*)d_in[3];

    int N = in_sizes[0] / D;            // 50000
    int E = in_sizes[2];                // 800000
    int L = in_sizes[1] / (D * D);      // 2 (composition assumes L==2)
    float invlp1 = 1.f / (float)(L + 1);
    int NBK = (N + BSIZE - 1) >> BSHIFT;  // 391
    int nebk = (E + EPB - 1) / EPB;       // 391

    char*  ws  = (char*)d_ws;
    size_t off = 0;
    auto alloc = [&](size_t bytes) -> void* {
        void* p = (void*)(ws + off);
        off += (bytes + 255) & ~(size_t)255;
        return p;
    };
    unsigned*       s8     = (unsigned*)alloc((size_t)N * 32 * sizeof(unsigned));  // fp8 rows (128 B)
    unsigned*       u8     = (unsigned*)alloc((size_t)N * 32 * sizeof(unsigned));  // fp8 rows (128 B)
    unsigned*       u16    = (unsigned*)alloc((size_t)N * 64 * sizeof(unsigned));  // bf16 rows (256 B)
    unsigned*       v16    = (unsigned*)alloc((size_t)N * 64 * sizeof(unsigned));  // bf16 rows (256 B)
    float*          Wc     = (float*)alloc((size_t)D * D * sizeof(float));
    unsigned short* wpack  = (unsigned short*)alloc((size_t)WTOT * 8 * sizeof(unsigned short));
    unsigned*       ebuf   = (unsigned*)alloc((size_t)NBK * BCAP * sizeof(unsigned));  // bucket-strided
    int*            colb   = (int*)alloc((size_t)NBK * BCAP * sizeof(int));            // bucket-strided
    int*            rps    = (int*)alloc((size_t)N * sizeof(int));
    int*            rdeg   = (int*)alloc((size_t)N * sizeof(int));
    int*            cur    = (int*)alloc((size_t)NBKMAX * sizeof(int));

    int packb = (N * 32 + 255) / 256;   // 6250
    int wcb   = (D * D + 255) / 256;    // 40
    int prepb = (WTOT + 255) / 256;     // 14

    // 1: pack | zero cur | Wc
    k_pre<<<packb + 1 + wcb, 256, 0, stream>>>(features, W, s8, Wc, cur, N, packb);
    // 2: bucketed edge dump (parallel per-edge dump) | W prepack
    k_sortC<<<nebk + prepb, 256, 0, stream>>>(src, dstv, cur, ebuf, E, NBK, nebk, W, Wc, wpack);
    // 3: per-bucket CSR finalize at fixed base
    k_csrD<<<NBK, 256, 0, stream>>>(ebuf, cur, colb, rps, rdeg, N, NBK);

    int spmmblocks = (N + 3) / 4;  // 4 waves x 1 node per block
    // 4: u = A*s0
    k_spmm<<<spmmblocks, 256, 0, stream>>>((const unsigned short*)s8, rps, rdeg, colb,
                                           (const unsigned*)nullptr,
                                           (unsigned short*)u8, u16, 1, N);
    // 5: v = A*u (self from bf16 u16)
    k_spmm<<<spmmblocks, 256, 0, stream>>>((const unsigned short*)u8, rps, rdeg, colb,
                                           u16, (unsigned short*)nullptr, v16, 0, N);

    // 6: epilogue (LDS-staged contiguous stores)
    int epiblocks = (N + 63) / 64;
    k_epi<<<epiblocks, 256, 0, stream>>>((const unsigned short*)u16, (const unsigned short*)v16,
                                         wpack, features, invlp1, (float*)d_out, N);
}